// Round 5
// baseline (1088.633 us; speedup 1.0000x reference)
//
#include <hip/hip_runtime.h>
#include <hip/hip_bf16.h>

typedef float f32x4 __attribute__((ext_vector_type(4)));
typedef short short8 __attribute__((ext_vector_type(8)));
typedef __hip_bfloat16 bf16;

constexpr int CDIM  = 384;
constexpr int LTOK  = 3136;      // 56*56
constexpr int NWIN  = 2048;      // 32 * 64 windows
constexpr int MROWS = 100352;    // NWIN * 49 = 784 panels x 128 rows
constexpr int MPAD  = MROWS + 64;
constexpr int NPANEL = 784;

__device__ __forceinline__ void gload_lds16(const void* g, void* l) {
  __builtin_amdgcn_global_load_lds(
      (const __attribute__((address_space(1))) void*)g,
      (__attribute__((address_space(3))) void*)l, 16, 0, 0);
}

// window-row r (w*49+n) -> (batch b, token l)
__device__ __forceinline__ void row_to_bl(int r, int& b, int& l) {
  int w = r / 49, n = r % 49;
  b = w >> 6;
  int wrem = w & 63;
  int wy = wrem >> 3, wx = wrem & 7;
  int ny = n / 7, nx = n % 7;
  l = (wy * 7 + ny) * 56 + wx * 7 + nx;
}

// ---------------- fused prep: mod GEMV | W retile (96-col slices) | bias table ----------------
// W layout per matrix: slice s (96 cols) contiguous 36864 elems:
//   i = ((s*12 + kt)*4 + g)*768 + nc*8 + j  <-  W[k = kt*32+g*8+j][n = s*96+nc]

__global__ __launch_bounds__(256) void prep_all(
    const float* __restrict__ cond, const float* __restrict__ mw,
    const float* __restrict__ mb, float* __restrict__ mod,
    const float* __restrict__ qw, const float* __restrict__ kvw,
    const float* __restrict__ pw,
    bf16* __restrict__ wtq, bf16* __restrict__ wtkv, bf16* __restrict__ wtp,
    const float* __restrict__ tab, float* __restrict__ bT) {
  int bid = blockIdx.x, t = threadIdx.x;
  if (bid < 96) {                               // mod = cond @ mod_w + mod_b
    int idx = bid * 256 + t;                    // 24576 exact
    int b = idx / 768, j = idx % 768;
    float s = mb[j];
    const float* cr = cond + b * 128;
    #pragma unroll 4
    for (int k = 0; k < 128; k++) s += cr[k] * mw[(size_t)k * 768 + j];
    mod[idx] = s;
  } else if (bid < 2400) {                      // weight retile, 589824 exact
    int idx = (bid - 96) * 256 + t;
    const float* src; bf16* dst; int i, Wn;
    if (idx < 147456)      { i = idx;          src = qw;  dst = wtq;  Wn = 384; }
    else if (idx < 442368) { i = idx - 147456; src = kvw; dst = wtkv; Wn = 768; }
    else                   { i = idx - 442368; src = pw;  dst = wtp;  Wn = 384; }
    int s = i / 36864, rem = i % 36864;
    int kt = rem / 3072, rem2 = rem % 3072;
    int g = rem2 / 768, rem3 = rem2 % 768;
    int nc = rem3 >> 3, j = rem3 & 7;
    int k = kt * 32 + g * 8 + j, n = s * 96 + nc;
    dst[i] = __float2bfloat16(src[(size_t)k * Wn + n]);
  } else {                                      // biasT[h][m][c], 49152 exact
    int idx = (bid - 2400) * 256 + t;
    int h = idx >> 12, rem = idx & 4095, m = rem >> 6, c = rem & 63;
    float v;
    if (c >= 49)      v = -1e30f;
    else if (m >= 49) v = 0.f;
    else {
      int yq = m / 7, xq = m % 7, yk = c / 7, xk = c % 7;
      v = tab[((yq - yk + 6) * 13 + (xq - xk + 6)) * 12 + h];
    }
    bT[idx] = v;
  }
}

// ---------------- LayerNorm (+AdaLN for x) -> tiled A layout, both streams in one launch ----------------
// aT element index: ((p*12 + kt)*4 + g)*1024 + rloc*8 + j
//   holds x_hat[row = p*128+rloc][col = kt*32+g*8+j]

__global__ __launch_bounds__(256) void ln_both(
    const float* __restrict__ x_tok, const float* __restrict__ gx,
    const float* __restrict__ bx, const float* __restrict__ modbuf,
    const float* __restrict__ z_tok, const float* __restrict__ gz,
    const float* __restrict__ bz,
    bf16* __restrict__ xT, bf16* __restrict__ zT) {
  int bid = blockIdx.x;
  bool isX = bid < 25088;
  const float* src   = isX ? x_tok : z_tok;
  const float* gamma = isX ? gx : gz;
  const float* beta  = isX ? bx : bz;
  const float* mod   = isX ? modbuf : nullptr;
  bf16* aT           = isX ? xT : zT;
  float eps          = isX ? 1e-6f : 1e-5f;
  int rb = (isX ? bid : bid - 25088) * 4;

  int wid = threadIdx.x >> 6, lane = threadIdx.x & 63;
  int r = rb + wid;
  int bb, ll; row_to_bl(r, bb, ll);
  const f32x4* x4 = (const f32x4*)(src + ((size_t)bb * LTOK + ll) * 384);
  const bool act = lane < 48;                 // lane = col-group (8 cols each)
  f32x4 a = {0,0,0,0}, b = {0,0,0,0};
  if (act) { a = x4[2 * lane]; b = x4[2 * lane + 1]; }
  float s  = a[0]+a[1]+a[2]+a[3]+b[0]+b[1]+b[2]+b[3];
  float s2 = a[0]*a[0]+a[1]*a[1]+a[2]*a[2]+a[3]*a[3]
           + b[0]*b[0]+b[1]*b[1]+b[2]*b[2]+b[3]*b[3];
  #pragma unroll
  for (int d = 1; d < 64; d <<= 1) { s += __shfl_xor(s, d); s2 += __shfl_xor(s2, d); }
  float mu = s * (1.f / 384.f);
  float var = s2 * (1.f / 384.f) - mu * mu;
  float rstd = rsqrtf(var + eps);
  if (!act) return;
  const f32x4* g4  = (const f32x4*)gamma;
  const f32x4* be4 = (const f32x4*)beta;
  f32x4 g0 = g4[2*lane], g1 = g4[2*lane+1], b0 = be4[2*lane], b1 = be4[2*lane+1];
  float o[8];
  if (mod != nullptr) {
    const f32x4* mg4 = (const f32x4*)(mod + bb * 768);
    const f32x4* mb4 = (const f32x4*)(mod + bb * 768 + 384);
    f32x4 m0 = mg4[2*lane], m1 = mg4[2*lane+1], n0 = mb4[2*lane], n1 = mb4[2*lane+1];
    #pragma unroll
    for (int i = 0; i < 4; i++) {
      o[i]     = (g0[i] * (1.f + m0[i])) * ((a[i] - mu) * rstd) + b0[i] + n0[i];
      o[4 + i] = (g1[i] * (1.f + m1[i])) * ((b[i] - mu) * rstd) + b1[i] + n1[i];
    }
  } else {
    #pragma unroll
    for (int i = 0; i < 4; i++) {
      o[i]     = (a[i] - mu) * rstd * g0[i] + b0[i];
      o[4 + i] = (b[i] - mu) * rstd * g1[i] + b1[i];
    }
  }
  short8 pk;
  #pragma unroll
  for (int i = 0; i < 8; i++)
    pk[i] = (short)__hip_bfloat16_raw(__float2bfloat16(o[i])).x;
  int p = r >> 7, rloc = r & 127;
  int kt = lane >> 2, g = lane & 3;
  *(short8*)(aT + ((size_t)(p * 12 + kt) * 4 + g) * 1024 + rloc * 8) = pk;
}

// ---------------- GEMM v5: W-slice resident in LDS, A streamed through registers ----------------
// Block owns a 96-col slice of W (73.7 KB LDS, staged once). No barriers in main loop.
// grid = (N/96) * BPS;  MODE 0: bf16 (acc+bias)*scale   MODE 1: f32 resid + window-unpermute

template<int MODE>
__global__ __launch_bounds__(256, 2) void gemm5(
    const bf16* __restrict__ aT, const bf16* __restrict__ WTt,
    const float* __restrict__ bias, void* __restrict__ outp,
    const float* __restrict__ resid, float scale, int N, int BPS) {
  __shared__ __align__(16) bf16 wS[36864];      // 96 cols x 384 k, MFMA-tiled
  const int t = threadIdx.x;
  const int wid = t >> 6, lane = t & 63;
  const int r16 = lane & 15, g = lane >> 4;
  const int s = blockIdx.x / BPS, bi = blockIdx.x % BPS;

  {
    const char* src = (const char*)WTt + (size_t)s * 73728;
    #pragma unroll
    for (int i = 0; i < 18; i++)
      gload_lds16(src + (i * 256 + t) * 16, (char*)wS + (i * 256 + t) * 16);
  }
  float bc[6];
  #pragma unroll
  for (int ni = 0; ni < 6; ni++) bc[ni] = bias[s * 96 + ni * 16 + r16];
  __syncthreads();                              // W resident; LDS read-only hereafter

  for (int p = bi; p < NPANEL; p += BPS) {
    short8 aF[2][12];
    #pragma unroll
    for (int m = 0; m < 2; m++)
      #pragma unroll
      for (int kt = 0; kt < 12; kt++)
        aF[m][kt] = *(const short8*)(aT + (((size_t)p * 12 + kt) * 4 + g) * 1024
                                         + (wid * 32 + m * 16 + r16) * 8);
    f32x4 acc[2][6] = {};
    #pragma unroll
    for (int kt = 0; kt < 12; kt++)
      #pragma unroll
      for (int ni = 0; ni < 6; ni++) {
        short8 bF = *(const short8*)(wS + ((size_t)(kt * 4 + g) * 96 + ni * 16 + r16) * 8);
        acc[0][ni] = __builtin_amdgcn_mfma_f32_16x16x32_bf16(aF[0][kt], bF, acc[0][ni], 0, 0, 0);
        acc[1][ni] = __builtin_amdgcn_mfma_f32_16x16x32_bf16(aF[1][kt], bF, acc[1][ni], 0, 0, 0);
      }

    if (MODE == 0) {
      bf16* O = (bf16*)outp;
      #pragma unroll
      for (int m = 0; m < 2; m++) {
        int row0 = p * 128 + wid * 32 + m * 16 + g * 4;
        #pragma unroll
        for (int rr = 0; rr < 4; rr++) {
          size_t rbase = (size_t)(row0 + rr) * N + s * 96;
          #pragma unroll
          for (int ni = 0; ni < 6; ni++)
            O[rbase + ni * 16 + r16] = __float2bfloat16((acc[m][ni][rr] + bc[ni]) * scale);
        }
      }
    } else {
      float* O = (float*)outp;
      #pragma unroll
      for (int m = 0; m < 2; m++) {
        #pragma unroll
        for (int rr = 0; rr < 4; rr++) {
          int row = p * 128 + wid * 32 + m * 16 + g * 4 + rr;
          int bb, ll; row_to_bl(row, bb, ll);
          size_t base = ((size_t)bb * LTOK + ll) * 384 + s * 96;
          #pragma unroll
          for (int ni = 0; ni < 6; ni++)
            O[base + ni * 16 + r16] = resid[base + ni * 16 + r16] + acc[m][ni][rr] + bc[ni];
        }
      }
    }
  }
}

// ---------------- attention: one wave per (window, head); writes TILED output ----------------

__global__ __launch_bounds__(64) void attn_kernel(
    const bf16* __restrict__ q, const bf16* __restrict__ kv,
    const float* __restrict__ biasT, bf16* __restrict__ aT) {
  __shared__ __align__(16) bf16 vt[32][72];     // V^T, padded
  __shared__ __align__(16) bf16 P[64][72];      // probs, padded
  __shared__ __align__(16) bf16 outS[49 * 40];  // out bounce, stride 40 elems (80 B)
  const int h = blockIdx.x, w = blockIdx.y;
  const int lane = threadIdx.x;
  const int r16 = lane & 15, g = lane >> 4;
  const size_t qbase = (size_t)w * 49 * 384 + h * 32;
  const size_t kvbase = (size_t)w * 49 * 768 + h * 32;

  // zero vt (pad cols must be 0), then fill V^T
  for (int e = lane; e < 32 * 72; e += 64) ((bf16*)vt)[e] = __float2bfloat16(0.f);
  for (int e = lane; e < 49 * 32; e += 64) {
    int c = e >> 5, d = e & 31;
    vt[d][c] = kv[kvbase + (size_t)c * 768 + 384 + d];
  }

  // QK^T: A and B fragments straight from global (both k-contiguous)
  short8 aq[4], bk[4];
  #pragma unroll
  for (int mi = 0; mi < 4; mi++)
    aq[mi] = *(const short8*)(q + qbase + (size_t)(mi * 16 + r16) * 384 + g * 8);
  #pragma unroll
  for (int ni = 0; ni < 4; ni++)
    bk[ni] = *(const short8*)(kv + kvbase + (size_t)(ni * 16 + r16) * 768 + g * 8);

  f32x4 zero = {0.f, 0.f, 0.f, 0.f};
  f32x4 S[4][4];
  #pragma unroll
  for (int mi = 0; mi < 4; mi++)
    #pragma unroll
    for (int ni = 0; ni < 4; ni++)
      S[mi][ni] = __builtin_amdgcn_mfma_f32_16x16x32_bf16(aq[mi], bk[ni], zero, 0, 0, 0);

  // bias + softmax (rows split over 16-lane groups; cols>=49 get -1e30 from biasT)
  const float* bt = biasT + h * 4096;
  #pragma unroll
  for (int mi = 0; mi < 4; mi++) {
    #pragma unroll
    for (int r = 0; r < 4; r++) {
      int rowm = mi * 16 + g * 4 + r;
      float sv[4];
      #pragma unroll
      for (int ni = 0; ni < 4; ni++)
        sv[ni] = S[mi][ni][r] + bt[rowm * 64 + ni * 16 + r16];
      float mx = fmaxf(fmaxf(sv[0], sv[1]), fmaxf(sv[2], sv[3]));
      #pragma unroll
      for (int d = 1; d < 16; d <<= 1) mx = fmaxf(mx, __shfl_xor(mx, d));
      float sum = 0.f;
      #pragma unroll
      for (int ni = 0; ni < 4; ni++) { sv[ni] = __expf(sv[ni] - mx); sum += sv[ni]; }
      #pragma unroll
      for (int d = 1; d < 16; d <<= 1) sum += __shfl_xor(sum, d);
      float inv = __fdividef(1.f, sum);
      #pragma unroll
      for (int ni = 0; ni < 4; ni++)
        P[rowm][ni * 16 + r16] = __float2bfloat16(sv[ni] * inv);
    }
  }
  __syncthreads();

  // PV
  f32x4 acc[4][2] = {};
  #pragma unroll
  for (int c0 = 0; c0 < 2; c0++) {
    short8 ap[4], bv[2];
    #pragma unroll
    for (int mi = 0; mi < 4; mi++)
      ap[mi] = *(const short8*)((const char*)&P[0][0] + (mi * 16 + r16) * 144 + c0 * 64 + g * 16);
    #pragma unroll
    for (int di = 0; di < 2; di++)
      bv[di] = *(const short8*)((const char*)&vt[0][0] + (di * 16 + r16) * 144 + c0 * 64 + g * 16);
    #pragma unroll
    for (int mi = 0; mi < 4; mi++)
      #pragma unroll
      for (int di = 0; di < 2; di++)
        acc[mi][di] = __builtin_amdgcn_mfma_f32_16x16x32_bf16(ap[mi], bv[di], acc[mi][di], 0, 0, 0);
  }

  // bounce through LDS, then write tiled layout: head h IS k-tile h (cols h*32..h*32+31)
  #pragma unroll
  for (int mi = 0; mi < 4; mi++) {
    #pragma unroll
    for (int r = 0; r < 4; r++) {
      int m = mi * 16 + g * 4 + r;
      if (m < 49) {
        #pragma unroll
        for (int di = 0; di < 2; di++)
          outS[m * 40 + di * 16 + r16] = __float2bfloat16(acc[mi][di][r]);
      }
    }
  }
  __syncthreads();
  for (int e = lane; e < 196; e += 64) {
    int m = e >> 2, j8 = e & 3;
    short8 v = *(const short8*)(outS + m * 40 + j8 * 8);
    int r = w * 49 + m, p = r >> 7, rloc = r & 127;
    *(short8*)(aT + ((size_t)(p * 12 + h) * 4 + j8) * 1024 + rloc * 8) = v;
  }
}

// ---------------- launch ----------------

extern "C" void kernel_launch(void* const* d_in, const int* in_sizes, int n_in,
                              void* d_out, int out_size, void* d_ws, size_t ws_size,
                              hipStream_t stream) {
  (void)in_sizes; (void)n_in; (void)out_size; (void)ws_size;
  const float* x_tok   = (const float*)d_in[0];
  const float* z_tok   = (const float*)d_in[1];
  const float* cond    = (const float*)d_in[2];
  const float* gamma_x = (const float*)d_in[3];
  const float* beta_x  = (const float*)d_in[4];
  const float* mod_w   = (const float*)d_in[5];
  const float* mod_b   = (const float*)d_in[6];
  const float* gamma_z = (const float*)d_in[7];
  const float* beta_z  = (const float*)d_in[8];
  const float* rel_tab = (const float*)d_in[9];
  const float* q_w     = (const float*)d_in[10];
  const float* q_b     = (const float*)d_in[11];
  const float* kv_w    = (const float*)d_in[12];
  const float* kv_b    = (const float*)d_in[13];
  const float* proj_w  = (const float*)d_in[14];
  const float* proj_b  = (const float*)d_in[15];

  char* ws = (char*)d_ws;
  float* modbuf = (float*)(ws + 0);                          //  98304 B
  bf16*  wtq    = (bf16*)(ws + 98304);                       // 294912 B (4 slices)
  bf16*  wtkv   = (bf16*)(ws + 98304 + 294912);              // 589824 B (8 slices)
  bf16*  wtp    = (bf16*)(ws + 98304 + 294912 + 589824);     // 294912 B (4 slices)
  float* biasT  = (float*)(ws + 98304 + 294912 + 589824 + 294912); // 196608 B
  char*  R1     = ws + 1474560;                              // x_hat tiled (77 MB)
  char*  R2     = R1 + (size_t)MPAD * 384 * 2;               // q row-major (+pad)
  char*  R3     = R2 + (size_t)MPAD * 384 * 2;               // kv row-major (+pad)
  char*  R4     = R3 + (size_t)MPAD * 768 * 2;               // z_hat tiled -> attn-out tiled

  // zero pad rows (attention fragment loads read past the last window)
  hipMemsetAsync(R2 + (size_t)MROWS * 384 * 2, 0, 64 * 384 * 2, stream);
  hipMemsetAsync(R3 + (size_t)MROWS * 768 * 2, 0, 64 * 768 * 2, stream);

  prep_all<<<2592, 256, 0, stream>>>(cond, mod_w, mod_b, modbuf,
                                     q_w, kv_w, proj_w, wtq, wtkv, wtp,
                                     rel_tab, biasT);
  ln_both<<<50176, 256, 0, stream>>>(x_tok, gamma_x, beta_x, modbuf,
                                     z_tok, gamma_z, beta_z,
                                     (bf16*)R1, (bf16*)R4);
  gemm5<0><<<512, 256, 0, stream>>>(
      (const bf16*)R1, wtq, q_b, R2, nullptr, 0.17677669529663687f, 384, 128);
  gemm5<0><<<512, 256, 0, stream>>>(
      (const bf16*)R4, wtkv, kv_b, R3, nullptr, 1.0f, 768, 64);
  attn_kernel<<<dim3(12, NWIN), 64, 0, stream>>>(
      (const bf16*)R2, (const bf16*)R3, biasT, (bf16*)R4);
  gemm5<1><<<512, 256, 0, stream>>>(
      (const bf16*)R4, wtp, proj_b, d_out, x_tok, 1.0f, 384, 128);
}

// Round 6
// 704.600 us; speedup vs baseline: 1.5450x; 1.5450x over previous
//
#include <hip/hip_runtime.h>
#include <hip/hip_bf16.h>

typedef float f32x4 __attribute__((ext_vector_type(4)));
typedef short short8 __attribute__((ext_vector_type(8)));
typedef __hip_bfloat16 bf16;

constexpr int CDIM  = 384;
constexpr int LTOK  = 3136;      // 56*56
constexpr int NWIN  = 2048;      // 32 * 64 windows
constexpr int MROWS = 100352;    // NWIN * 49 = 1568 panels x 64 rows
constexpr int MPAD  = MROWS + 64;
constexpr int NP64  = 1568;      // 64-row panels

__device__ __forceinline__ void gload_lds16(const void* g, void* l) {
  __builtin_amdgcn_global_load_lds(
      (const __attribute__((address_space(1))) void*)g,
      (__attribute__((address_space(3))) void*)l, 16, 0, 0);
}

// window-row r (w*49+n) -> (batch b, token l)
__device__ __forceinline__ void row_to_bl(int r, int& b, int& l) {
  int w = r / 49, n = r % 49;
  b = w >> 6;
  int wrem = w & 63;
  int wy = wrem >> 3, wx = wrem & 7;
  int ny = n / 7, nx = n % 7;
  l = (wy * 7 + ny) * 56 + wx * 7 + nx;
}

// ---------------- fused prep: mod GEMV | W retile (64-col slices) | bias table ----------------
// W tiled layout, flat elem: i = ((s*12 + kt)*4 + g)*512 + nc*8 + j
//   holds W[k = kt*32 + g*8 + j][n = s*64 + nc]   (one slice = 24576 elems = 48 KB)

__global__ __launch_bounds__(256) void prep_all(
    const float* __restrict__ cond, const float* __restrict__ mw,
    const float* __restrict__ mb, float* __restrict__ mod,
    const float* __restrict__ qw, const float* __restrict__ kvw,
    const float* __restrict__ pw,
    bf16* __restrict__ wtq, bf16* __restrict__ wtkv, bf16* __restrict__ wtp,
    const float* __restrict__ tab, float* __restrict__ bT) {
  int bid = blockIdx.x, t = threadIdx.x;
  if (bid < 96) {                               // mod = cond @ mod_w + mod_b
    int idx = bid * 256 + t;                    // 24576 exact
    int b = idx / 768, j = idx % 768;
    float s = mb[j];
    const float* cr = cond + b * 128;
    #pragma unroll 4
    for (int k = 0; k < 128; k++) s += cr[k] * mw[(size_t)k * 768 + j];
    mod[idx] = s;
  } else if (bid < 2400) {                      // weight retile, 589824 exact
    int idx = (bid - 96) * 256 + t;
    const float* src; bf16* dst; int i, Wn;
    if (idx < 147456)      { i = idx;          src = qw;  dst = wtq;  Wn = 384; }
    else if (idx < 442368) { i = idx - 147456; src = kvw; dst = wtkv; Wn = 768; }
    else                   { i = idx - 442368; src = pw;  dst = wtp;  Wn = 384; }
    int j = i & 7, nc = (i >> 3) & 63, g = (i >> 9) & 3;
    int kt = (i >> 11) % 12, s = i / 24576;
    int k = kt * 32 + g * 8 + j, n = s * 64 + nc;
    dst[i] = __float2bfloat16(src[(size_t)k * Wn + n]);
  } else {                                      // biasT[h][m][c], 49152 exact
    int idx = (bid - 2400) * 256 + t;
    int h = idx >> 12, rem = idx & 4095, m = rem >> 6, c = rem & 63;
    float v;
    if (c >= 49)      v = -1e30f;
    else if (m >= 49) v = 0.f;
    else {
      int yq = m / 7, xq = m % 7, yk = c / 7, xk = c % 7;
      v = tab[((yq - yk + 6) * 13 + (xq - xk + 6)) * 12 + h];
    }
    bT[idx] = v;
  }
}

// ---------------- LayerNorm (+AdaLN for x), row-major bf16 out, both streams ----------------

struct alignas(8) B4 { bf16 h[4]; };

__global__ __launch_bounds__(256) void ln_both(
    const float* __restrict__ x_tok, const float* __restrict__ gx,
    const float* __restrict__ bx, const float* __restrict__ modbuf,
    const float* __restrict__ z_tok, const float* __restrict__ gz,
    const float* __restrict__ bz,
    bf16* __restrict__ xO, bf16* __restrict__ zO) {
  int bid = blockIdx.x;
  bool isX = bid < 25088;
  const float* src   = isX ? x_tok : z_tok;
  const float* gamma = isX ? gx : gz;
  const float* beta  = isX ? bx : bz;
  const float* mod   = isX ? modbuf : nullptr;
  bf16* dst          = isX ? xO : zO;
  float eps          = isX ? 1e-6f : 1e-5f;
  int rb = (isX ? bid : bid - 25088) * 4;

  int wid = threadIdx.x >> 6, lane = threadIdx.x & 63;
  int r = rb + wid;
  int bb, ll; row_to_bl(r, bb, ll);
  const f32x4* x4 = (const f32x4*)(src + ((size_t)bb * LTOK + ll) * 384);
  f32x4 a = x4[lane];
  f32x4 b = {0.f, 0.f, 0.f, 0.f};
  if (lane < 32) b = x4[64 + lane];
  float s  = a[0] + a[1] + a[2] + a[3] + b[0] + b[1] + b[2] + b[3];
  float s2 = a[0]*a[0] + a[1]*a[1] + a[2]*a[2] + a[3]*a[3]
           + b[0]*b[0] + b[1]*b[1] + b[2]*b[2] + b[3]*b[3];
  #pragma unroll
  for (int d = 1; d < 64; d <<= 1) { s += __shfl_xor(s, d); s2 += __shfl_xor(s2, d); }
  float mu = s * (1.f / 384.f);
  float var = s2 * (1.f / 384.f) - mu * mu;
  float rstd = rsqrtf(var + eps);
  bf16* o = dst + (size_t)r * 384;
  const f32x4* g4 = (const f32x4*)gamma;
  const f32x4* be4 = (const f32x4*)beta;
  if (mod != nullptr) {
    const f32x4* mg4 = (const f32x4*)(mod + bb * 768);
    const f32x4* mb4 = (const f32x4*)(mod + bb * 768 + 384);
    {
      f32x4 gg = g4[lane], bb2 = be4[lane], mg = mg4[lane], mb = mb4[lane];
      B4 p;
      #pragma unroll
      for (int i = 0; i < 4; i++)
        p.h[i] = __float2bfloat16((gg[i] * (1.f + mg[i])) * ((a[i] - mu) * rstd) + bb2[i] + mb[i]);
      *((B4*)o + lane) = p;
    }
    if (lane < 32) {
      f32x4 gg = g4[64 + lane], bb2 = be4[64 + lane], mg = mg4[64 + lane], mb = mb4[64 + lane];
      B4 p;
      #pragma unroll
      for (int i = 0; i < 4; i++)
        p.h[i] = __float2bfloat16((gg[i] * (1.f + mg[i])) * ((b[i] - mu) * rstd) + bb2[i] + mb[i]);
      *((B4*)o + 64 + lane) = p;
    }
  } else {
    {
      f32x4 gg = g4[lane], bb2 = be4[lane];
      B4 p;
      #pragma unroll
      for (int i = 0; i < 4; i++)
        p.h[i] = __float2bfloat16((a[i] - mu) * rstd * gg[i] + bb2[i]);
      *((B4*)o + lane) = p;
    }
    if (lane < 32) {
      f32x4 gg = g4[64 + lane], bb2 = be4[64 + lane];
      B4 p;
      #pragma unroll
      for (int i = 0; i < 4; i++)
        p.h[i] = __float2bfloat16((b[i] - mu) * rstd * gg[i] + bb2[i]);
      *((B4*)o + 64 + lane) = p;
    }
  }
}

// ---------------- GEMM v6: W-slice (64 cols) resident in LDS; A streamed row-major; ----------------
// slice-interleaved grid (s = bid % NS) so concurrent blocks share A through L2/L3.
// No barriers in main loop. grid = NS * BPS = 768 (one occupancy round at 3 blocks/CU).
// MODE 0: bf16 (acc+bias)*scale   MODE 1: f32 resid + window-unpermute

template<int MODE>
__global__ __launch_bounds__(256, 4) void gemm6(
    const bf16* __restrict__ A, const bf16* __restrict__ WTt,
    const float* __restrict__ bias, void* __restrict__ outp,
    const float* __restrict__ resid, float scale, int N, int NS, int BPS) {
  __shared__ __align__(16) bf16 wS[24576];      // 64 cols x 384 k, MFMA-tiled (48 KB)
  const int t = threadIdx.x;
  const int wid = t >> 6, lane = t & 63;
  const int r16 = lane & 15, g = lane >> 4;
  const int s = blockIdx.x % NS, bi = blockIdx.x / NS;

  {
    const char* src = (const char*)WTt + (size_t)s * 49152;
    #pragma unroll
    for (int i = 0; i < 12; i++)
      gload_lds16(src + (i * 256 + t) * 16, (char*)wS + (i * 256 + t) * 16);
  }
  float bc[4];
  #pragma unroll
  for (int ni = 0; ni < 4; ni++) bc[ni] = bias[s * 64 + ni * 16 + r16];
  __syncthreads();                              // W resident; LDS read-only hereafter

  for (int p = bi; p < NP64; p += BPS) {
    const int prow = p * 64 + wid * 16;         // wave owns 16 rows x 64 cols

    short8 aF[12];
    #pragma unroll
    for (int kt = 0; kt < 12; kt++)
      aF[kt] = *(const short8*)(A + (size_t)(prow + r16) * 384 + kt * 32 + g * 8);

    f32x4 acc[4] = {};
    #pragma unroll
    for (int kt = 0; kt < 12; kt++) {
      #pragma unroll
      for (int ni = 0; ni < 4; ni++) {
        short8 wF = *(const short8*)((const char*)wS + (kt * 4 + g) * 1024 + (ni * 16 + r16) * 16);
        acc[ni] = __builtin_amdgcn_mfma_f32_16x16x32_bf16(aF[kt], wF, acc[ni], 0, 0, 0);
      }
    }

    if (MODE == 0) {
      bf16* O = (bf16*)outp;
      #pragma unroll
      for (int rr = 0; rr < 4; rr++) {
        size_t rbase = (size_t)(prow + g * 4 + rr) * N + s * 64;
        #pragma unroll
        for (int ni = 0; ni < 4; ni++)
          O[rbase + ni * 16 + r16] = __float2bfloat16((acc[ni][rr] + bc[ni]) * scale);
      }
    } else {
      float* O = (float*)outp;
      #pragma unroll
      for (int rr = 0; rr < 4; rr++) {
        int row = prow + g * 4 + rr;
        int bb, ll; row_to_bl(row, bb, ll);
        size_t base = ((size_t)bb * LTOK + ll) * 384 + s * 64;
        #pragma unroll
        for (int ni = 0; ni < 4; ni++)
          O[base + ni * 16 + r16] = resid[base + ni * 16 + r16] + acc[ni][rr] + bc[ni];
      }
    }
  }
}

// ---------------- attention: one wave per (window, head), row-major out ----------------

__global__ __launch_bounds__(64) void attn_kernel(
    const bf16* __restrict__ q, const bf16* __restrict__ kv,
    const float* __restrict__ biasT, bf16* __restrict__ o) {
  __shared__ __align__(16) bf16 vt[32][72];   // V^T, padded
  __shared__ __align__(16) bf16 P[64][72];    // probs, padded
  const int h = blockIdx.x, w = blockIdx.y;
  const int lane = threadIdx.x;
  const int r16 = lane & 15, g = lane >> 4;
  const size_t qbase = (size_t)w * 49 * 384 + h * 32;
  const size_t kvbase = (size_t)w * 49 * 768 + h * 32;

  // zero vt (pad cols must be 0, LDS is uninitialized), then fill V^T
  for (int e = lane; e < 32 * 72; e += 64) ((bf16*)vt)[e] = __float2bfloat16(0.f);
  for (int e = lane; e < 49 * 32; e += 64) {
    int c = e >> 5, d = e & 31;
    vt[d][c] = kv[kvbase + (size_t)c * 768 + 384 + d];
  }

  // QK^T: A and B fragments straight from global (both k-contiguous)
  short8 aq[4], bk[4];
  #pragma unroll
  for (int mi = 0; mi < 4; mi++)
    aq[mi] = *(const short8*)(q + qbase + (size_t)(mi * 16 + r16) * 384 + g * 8);
  #pragma unroll
  for (int ni = 0; ni < 4; ni++)
    bk[ni] = *(const short8*)(kv + kvbase + (size_t)(ni * 16 + r16) * 768 + g * 8);

  f32x4 zero = {0.f, 0.f, 0.f, 0.f};
  f32x4 S[4][4];
  #pragma unroll
  for (int mi = 0; mi < 4; mi++)
    #pragma unroll
    for (int ni = 0; ni < 4; ni++)
      S[mi][ni] = __builtin_amdgcn_mfma_f32_16x16x32_bf16(aq[mi], bk[ni], zero, 0, 0, 0);

  // bias + softmax (rows split over 16-lane groups; cols>=49 get -1e30 from biasT)
  const float* bt = biasT + h * 4096;
  #pragma unroll
  for (int mi = 0; mi < 4; mi++) {
    #pragma unroll
    for (int r = 0; r < 4; r++) {
      int rowm = mi * 16 + g * 4 + r;
      float sv[4];
      #pragma unroll
      for (int ni = 0; ni < 4; ni++)
        sv[ni] = S[mi][ni][r] + bt[rowm * 64 + ni * 16 + r16];
      float mx = fmaxf(fmaxf(sv[0], sv[1]), fmaxf(sv[2], sv[3]));
      #pragma unroll
      for (int d = 1; d < 16; d <<= 1) mx = fmaxf(mx, __shfl_xor(mx, d));
      float sum = 0.f;
      #pragma unroll
      for (int ni = 0; ni < 4; ni++) { sv[ni] = __expf(sv[ni] - mx); sum += sv[ni]; }
      #pragma unroll
      for (int d = 1; d < 16; d <<= 1) sum += __shfl_xor(sum, d);
      float inv = __fdividef(1.f, sum);
      #pragma unroll
      for (int ni = 0; ni < 4; ni++)
        P[rowm][ni * 16 + r16] = __float2bfloat16(sv[ni] * inv);
    }
  }
  __syncthreads();

  // PV
  f32x4 acc[4][2] = {};
  #pragma unroll
  for (int c0 = 0; c0 < 2; c0++) {
    short8 ap[4], bv[2];
    #pragma unroll
    for (int mi = 0; mi < 4; mi++)
      ap[mi] = *(const short8*)((const char*)&P[0][0] + (mi * 16 + r16) * 144 + c0 * 64 + g * 16);
    #pragma unroll
    for (int di = 0; di < 2; di++)
      bv[di] = *(const short8*)((const char*)&vt[0][0] + (di * 16 + r16) * 144 + c0 * 64 + g * 16);
    #pragma unroll
    for (int mi = 0; mi < 4; mi++)
      #pragma unroll
      for (int di = 0; di < 2; di++)
        acc[mi][di] = __builtin_amdgcn_mfma_f32_16x16x32_bf16(ap[mi], bv[di], acc[mi][di], 0, 0, 0);
  }

  #pragma unroll
  for (int mi = 0; mi < 4; mi++) {
    #pragma unroll
    for (int r = 0; r < 4; r++) {
      int m = mi * 16 + g * 4 + r;
      if (m < 49) {
        #pragma unroll
        for (int di = 0; di < 2; di++)
          o[(size_t)(w * 49 + m) * 384 + h * 32 + di * 16 + r16] =
              __float2bfloat16(acc[mi][di][r]);
      }
    }
  }
}

// ---------------- launch ----------------

extern "C" void kernel_launch(void* const* d_in, const int* in_sizes, int n_in,
                              void* d_out, int out_size, void* d_ws, size_t ws_size,
                              hipStream_t stream) {
  (void)in_sizes; (void)n_in; (void)out_size; (void)ws_size;
  const float* x_tok   = (const float*)d_in[0];
  const float* z_tok   = (const float*)d_in[1];
  const float* cond    = (const float*)d_in[2];
  const float* gamma_x = (const float*)d_in[3];
  const float* beta_x  = (const float*)d_in[4];
  const float* mod_w   = (const float*)d_in[5];
  const float* mod_b   = (const float*)d_in[6];
  const float* gamma_z = (const float*)d_in[7];
  const float* beta_z  = (const float*)d_in[8];
  const float* rel_tab = (const float*)d_in[9];
  const float* q_w     = (const float*)d_in[10];
  const float* q_b     = (const float*)d_in[11];
  const float* kv_w    = (const float*)d_in[12];
  const float* kv_b    = (const float*)d_in[13];
  const float* proj_w  = (const float*)d_in[14];
  const float* proj_b  = (const float*)d_in[15];

  char* ws = (char*)d_ws;
  float* modbuf = (float*)(ws + 0);                          //  98304 B
  bf16*  wtq    = (bf16*)(ws + 98304);                       // 294912 B  (6 slices)
  bf16*  wtkv   = (bf16*)(ws + 98304 + 294912);              // 589824 B  (12 slices)
  bf16*  wtp    = (bf16*)(ws + 98304 + 294912 + 589824);     // 294912 B  (6 slices)
  float* biasT  = (float*)(ws + 98304 + 294912 + 589824 + 294912); // 196608 B
  char*  R1     = ws + 1474560;                              // x_hat -> attn_out (row-major)
  char*  R2     = R1 + (size_t)MPAD * 384 * 2;               // q row-major (+pad)
  char*  R3     = R2 + (size_t)MPAD * 384 * 2;               // kv row-major (+pad)
  char*  R4     = R3 + (size_t)MPAD * 768 * 2;               // z_hat row-major

  // zero pad rows (attention fragment loads read past the last window)
  hipMemsetAsync(R2 + (size_t)MROWS * 384 * 2, 0, 64 * 384 * 2, stream);
  hipMemsetAsync(R3 + (size_t)MROWS * 768 * 2, 0, 64 * 768 * 2, stream);

  prep_all<<<2592, 256, 0, stream>>>(cond, mod_w, mod_b, modbuf,
                                     q_w, kv_w, proj_w, wtq, wtkv, wtp,
                                     rel_tab, biasT);
  ln_both<<<50176, 256, 0, stream>>>(x_tok, gamma_x, beta_x, modbuf,
                                     z_tok, gamma_z, beta_z,
                                     (bf16*)R1, (bf16*)R4);
  gemm6<0><<<768, 256, 0, stream>>>(
      (const bf16*)R1, wtq, q_b, R2, nullptr, 0.17677669529663687f, 384, 6, 128);
  gemm6<0><<<768, 256, 0, stream>>>(
      (const bf16*)R4, wtkv, kv_b, R3, nullptr, 1.0f, 768, 12, 64);
  attn_kernel<<<dim3(12, NWIN), 64, 0, stream>>>(
      (const bf16*)R2, (const bf16*)R3, biasT, (bf16*)R1);
  gemm6<1><<<768, 256, 0, stream>>>(
      (const bf16*)R1, wtp, proj_b, d_out, x_tok, 1.0f, 384, 6, 128);
}